// Round 14
// baseline (1225.185 us; speedup 1.0000x reference)
//
#include <hip/hip_runtime.h>
#include <hip/hip_bf16.h>
#include <math.h>

#define NN 50000
#define EE 800000
#define HH 8
#define DD 16
#define HDIM 128
#define LL 6
#define GG 64
#define NDI 48
#define EDI 4
#define FFD 512
#define SCB ((NN + 1023) / 1024)   // scan blocks = 49

typedef __attribute__((ext_vector_type(8))) short short8;
typedef __attribute__((ext_vector_type(8))) unsigned short ushort8;
typedef __attribute__((ext_vector_type(4))) float floatx4;
typedef __attribute__((ext_vector_type(2))) float f32x2;

__device__ __forceinline__ unsigned short f2bf(float f) {
  unsigned u = __builtin_bit_cast(unsigned, f);
  unsigned rnd = 0x7FFFu + ((u >> 16) & 1u);
  return (unsigned short)((u + rnd) >> 16);
}
__device__ __forceinline__ float bf2f(unsigned short u) {
  unsigned v = ((unsigned)u) << 16;
  return __builtin_bit_cast(float, v);
}

#ifdef __has_builtin
#if __has_builtin(__builtin_amdgcn_cvt_pk_f32_fp8) && __has_builtin(__builtin_amdgcn_cvt_pk_fp8_f32)
#define HW_FP8 1
#endif
#endif

// e4m3 encode (single value)
__device__ __forceinline__ unsigned char f2fp8(float f) {
#ifdef HW_FP8
  int p = __builtin_amdgcn_cvt_pk_fp8_f32(f, 0.f, 0, false);
  return (unsigned char)(p & 0xff);
#else
  unsigned u = __builtin_bit_cast(unsigned, f);
  unsigned s = (u >> 24) & 0x80u;
  unsigned au = u & 0x7fffffffu;
  float a = __builtin_bit_cast(float, au);
  if (a >= 448.f) return (unsigned char)(s | 0x7e);
  if (a < 0.0009765625f) return (unsigned char)s;  // < 2^-10 -> 0
  int e32 = (int)(au >> 23) - 127;
  if (e32 >= -6) {
    au += (1u << 19);  // round-to-nearest (half ulp of 3-bit mantissa)
    e32 = (int)(au >> 23) - 127;
    if (e32 > 8) return (unsigned char)(s | 0x7e);
    unsigned m = (au >> 20) & 7u;
    return (unsigned char)(s | (unsigned)((e32 + 7) << 3) | m);
  } else {
    int m = (int)(a * 512.f + 0.5f);
    if (m > 7) return (unsigned char)(s | 0x08);
    return (unsigned char)(s | (unsigned)m);
  }
#endif
}

// decode 8 fp8 (uint2) -> float[8]
__device__ __forceinline__ void fp8x8_dec(uint2 kw, float* f) {
#ifdef HW_FP8
  f32x2 a = __builtin_amdgcn_cvt_pk_f32_fp8((int)kw.x, false);
  f32x2 b = __builtin_amdgcn_cvt_pk_f32_fp8((int)kw.x, true);
  f32x2 c = __builtin_amdgcn_cvt_pk_f32_fp8((int)kw.y, false);
  f32x2 d = __builtin_amdgcn_cvt_pk_f32_fp8((int)kw.y, true);
  f[0] = a[0]; f[1] = a[1]; f[2] = b[0]; f[3] = b[1];
  f[4] = c[0]; f[5] = c[1]; f[6] = d[0]; f[7] = d[1];
#else
  unsigned w[2] = {kw.x, kw.y};
#pragma unroll
  for (int i = 0; i < 8; i++) {
    unsigned char bb = (unsigned char)((w[i >> 2] >> ((i & 3) * 8)) & 0xff);
    unsigned s = ((unsigned)bb & 0x80u) << 24;
    unsigned e = (bb >> 3) & 0xFu;
    unsigned m = bb & 7u;
    float v;
    if (e == 0) v = (float)m * 0.001953125f;
    else v = __builtin_bit_cast(float, ((e + 120u) << 23) | (m << 20));
    f[i] = __builtin_bit_cast(float, __builtin_bit_cast(unsigned, v) | s);
  }
#endif
}

// ---------------- node input projection: x = h @ node_W + node_b (fp32) ----------------
__global__ void k_node_proj(const float* __restrict__ h, const float* __restrict__ W,
                            const float* __restrict__ b, float* __restrict__ x) {
  __shared__ float hs[32][NDI];
  int t = threadIdx.x;                 // 128
  int n0 = blockIdx.x * 32;
  for (int idx = t; idx < 32 * NDI; idx += 128) {
    int nb = idx / NDI, i = idx - nb * NDI;
    int node = n0 + nb;
    hs[nb][i] = (node < NN) ? h[node * NDI + i] : 0.f;
  }
  __syncthreads();
  float acc[32];
#pragma unroll
  for (int nb = 0; nb < 32; nb++) acc[nb] = 0.f;
  for (int i = 0; i < NDI; i++) {
    float w = W[i * HDIM + t];
#pragma unroll
    for (int nb = 0; nb < 32; nb++) acc[nb] += hs[nb][i] * w;
  }
  float bb = b[t];
  for (int nb = 0; nb < 32; nb++) {
    int node = n0 + nb;
    if (node < NN) x[node * HDIM + t] = acc[nb] + bb;
  }
}

// ------- weight fragment pre-pack: W[m][K][OC] fp32 -> [m][OC/16][K/32][64][8] bf16 -------
// scale is a power of two (1.0 or 0.25) -> f2bf(scale*w) is bit-exactly scale*f2bf(w)
__global__ void k_pack(const float* __restrict__ W, unsigned short* __restrict__ dst,
                       int K, int OC, int nmat, float scale) {
  int KC = K >> 5, CT = OC >> 4;
  int total = nmat * CT * KC * 512;
  for (int i = blockIdx.x * 256 + threadIdx.x; i < total; i += gridDim.x * 256) {
    int j = i & 7;
    int lane = (i >> 3) & 63;
    int rest = i >> 9;
    int kc = rest % KC; rest /= KC;
    int ct = rest % CT; int m = rest / CT;
    int col = ct * 16 + (lane & 15);
    int k = kc * 32 + (lane >> 4) * 8 + j;
    dst[i] = f2bf(scale * W[(size_t)m * K * OC + (size_t)k * OC + col]);
  }
}

// ------- combined edge-bias matrices: Wcomb[l] = edge_W @ Web[l]  [4x8], bcomb -------
__global__ void k_wcomb(const float* __restrict__ edge_W, const float* __restrict__ edge_b,
                        const float* __restrict__ Web, const float* __restrict__ beb,
                        float* __restrict__ Wcomb, float* __restrict__ bcomb) {
  int t = threadIdx.x;  // 256
  if (t < LL * EDI * HH) {  // 192
    int l = t / (EDI * HH);
    int i = (t / HH) % EDI;
    int hh = t % HH;
    float s = 0.f;
    for (int j = 0; j < HDIM; j++) s += edge_W[i * HDIM + j] * Web[(l * HDIM + j) * HH + hh];
    Wcomb[t] = s;
  } else if (t < LL * EDI * HH + LL * HH) {  // next 48
    int u = t - LL * EDI * HH;
    int l = u / HH, hh = u % HH;
    float s = beb[l * HH + hh];
    for (int j = 0; j < HDIM; j++) s += edge_b[j] * Web[(l * HDIM + j) * HH + hh];
    bcomb[u] = s;
  }
}

// ---------------- CSR build ----------------
__global__ void k_deg(const int* __restrict__ row, int* __restrict__ deg) {
  int e = blockIdx.x * 256 + threadIdx.x;
  if (e < EE) atomicAdd(&deg[row[e]], 1);
}

__global__ void k_scan1(const int* __restrict__ deg, int* __restrict__ bsum) {
  __shared__ int red[256];
  int b = blockIdx.x, t = threadIdx.x;
  int base = b * 1024;
  int s = 0;
  for (int j = t; j < 1024; j += 256) {
    int i = base + j;
    s += (i < NN) ? deg[i] : 0;
  }
  red[t] = s;
  __syncthreads();
  for (int off = 128; off > 0; off >>= 1) {
    if (t < off) red[t] += red[t + off];
    __syncthreads();
  }
  if (t == 0) bsum[b] = red[0];
}

__global__ void k_scan2(int* __restrict__ bsum, int* __restrict__ starts) {
  if (threadIdx.x == 0) {
    int s = 0;
    for (int b = 0; b < SCB; b++) { int v = bsum[b]; bsum[b] = s; s += v; }
    starts[NN] = s;
  }
}

__global__ void k_scan3(const int* __restrict__ deg, const int* __restrict__ bsum,
                        int* __restrict__ starts, int* __restrict__ cursor) {
  __shared__ int tsum[256];
  int b = blockIdx.x, t = threadIdx.x;
  int base = b * 1024 + t * 4;
  int v[4];
  int s = 0;
#pragma unroll
  for (int j = 0; j < 4; j++) {
    int i = base + j;
    v[j] = (i < NN) ? deg[i] : 0;
    s += v[j];
  }
  tsum[t] = s;
  __syncthreads();
  for (int off = 1; off < 256; off <<= 1) {
    int xv = (t >= off) ? tsum[t - off] : 0;
    __syncthreads();
    tsum[t] += xv;
    __syncthreads();
  }
  int excl = tsum[t] - s + bsum[b];
#pragma unroll
  for (int j = 0; j < 4; j++) {
    int i = base + j;
    if (i < NN) { starts[i] = excl; cursor[i] = excl; excl += v[j]; }
  }
}

// scatter writes CSR edge ids AND direct column ids
__global__ void k_scatter(const int* __restrict__ row, const int* __restrict__ col,
                          int* __restrict__ cursor,
                          int* __restrict__ eids, int* __restrict__ cols) {
  int e = blockIdx.x * 256 + threadIdx.x;
  if (e < EE) {
    int r = row[e];
    int pos = atomicAdd(&cursor[r], 1);
    eids[pos] = e;
    cols[pos] = col[e];
  }
}

// ---------------- graph ranges from sorted batch: boundary detection ----------------
__global__ void k_gbounds(const int* __restrict__ batch, int* __restrict__ gstart) {
  int i = blockIdx.x * 256 + threadIdx.x;
  if (i >= NN) return;
  int b = batch[i];
  int prev = (i == 0) ? -1 : batch[i - 1];
  for (int g = prev + 1; g <= b; g++) gstart[g] = i;
  if (i == NN - 1) {
    for (int g = b + 1; g <= GG; g++) gstart[g] = NN;
  }
}

// ---------------- per-layer edge bias in CSR order: ebias[i][h] (bf16) ----------------
__global__ void k_ebias(const int* __restrict__ eids, const float* __restrict__ efeat,
                        const float* __restrict__ Wcomb, const float* __restrict__ bcomb,
                        unsigned short* __restrict__ ebias) {
  int i = blockIdx.x * 256 + threadIdx.x;
  if (i >= EE) return;
  int e = eids[i];
  float4 ef = *(const float4*)(efeat + (size_t)e * EDI);
  ushort8 o;
#pragma unroll
  for (int hh = 0; hh < HH; hh++) {
    o[hh] = f2bf(bcomb[hh] + ef.x * Wcomb[hh] + ef.y * Wcomb[8 + hh] +
                 ef.z * Wcomb[16 + hh] + ef.w * Wcomb[24 + hh]);
  }
  *(ushort8*)(ebias + (size_t)i * 8) = o;
}

// ---------------- all-layers edge bias (prologue, when workspace allows) ----------------
__global__ void k_ebias_all(const int* __restrict__ eids, const float* __restrict__ efeat,
                            const float* __restrict__ WcombAll,
                            const float* __restrict__ bcombAll,
                            unsigned short* __restrict__ ebias6) {
  int i = blockIdx.x * 256 + threadIdx.x;
  if (i >= EE) return;
  int e = eids[i];
  float4 ef = *(const float4*)(efeat + (size_t)e * EDI);
#pragma unroll
  for (int l = 0; l < LL; l++) {
    const float* Wc = WcombAll + l * 32;
    const float* bc = bcombAll + l * 8;
    ushort8 o;
#pragma unroll
    for (int hh = 0; hh < HH; hh++) {
      o[hh] = f2bf(bc[hh] + ef.x * Wc[hh] + ef.y * Wc[8 + hh] +
                   ef.z * Wc[16 + hh] + ef.w * Wc[24 + hh]);
    }
    *(ushort8*)(ebias6 + ((size_t)l * EE + i) * 8) = o;
  }
}

// ---------------- LN1 + QKV projection via MFMA: 64 nodes/block, 4 waves ----------------
// outputs: q bf16 [node][128] (pre-scaled by 0.25 via packed Wq/bq), kf8, vf8 fp8
__global__ __launch_bounds__(256) void k_ln_qkv_mfma(
    const float* __restrict__ x,
    const unsigned short* __restrict__ Wqf, const float* __restrict__ bq,
    const unsigned short* __restrict__ Wkf, const float* __restrict__ bk,
    const unsigned short* __restrict__ Wvf, const float* __restrict__ bv,
    const float* __restrict__ g, const float* __restrict__ be,
    unsigned short* __restrict__ q, unsigned char* __restrict__ kf8,
    unsigned char* __restrict__ vf8) {
  __shared__ unsigned short xn[64][136];
  int t = threadIdx.x;
  int n0 = blockIdx.x * 64;
  {
    int row = t >> 2, quad = t & 3;   // 4 lanes/row, 32 elems each
    int node = n0 + row;
    float xv[32];
    float s = 0.f, sq = 0.f;
    if (node < NN) {
      const float* xr = x + (size_t)node * HDIM + quad * 32;
#pragma unroll
      for (int c = 0; c < 8; c++) {
        float4 f = *(const float4*)(xr + c * 4);
        xv[c*4+0]=f.x; xv[c*4+1]=f.y; xv[c*4+2]=f.z; xv[c*4+3]=f.w;
      }
#pragma unroll
      for (int j = 0; j < 32; j++) { s += xv[j]; sq += xv[j]*xv[j]; }
    } else {
#pragma unroll
      for (int j = 0; j < 32; j++) xv[j] = 0.f;
    }
    s += __shfl_xor(s, 1); s += __shfl_xor(s, 2);
    sq += __shfl_xor(sq, 1); sq += __shfl_xor(sq, 2);
    float m = s * (1.f / HDIM);
    float rv = rsqrtf(sq * (1.f / HDIM) - m * m + 1e-5f);
#pragma unroll
    for (int cb = 0; cb < 4; cb++) {
      ushort8 u;
#pragma unroll
      for (int j = 0; j < 8; j++) {
        int col = quad * 32 + cb * 8 + j;
        u[j] = f2bf((xv[cb*8+j] - m) * rv * g[col] + be[col]);
      }
      *(ushort8*)&xn[row][quad * 32 + cb * 8] = u;
    }
  }
  __syncthreads();
  int w = t >> 6, lane = t & 63;
  int r0 = w * 16;
  short8 a[4];
#pragma unroll
  for (int kc = 0; kc < 4; kc++)
    a[kc] = *(const short8*)&xn[r0 + (lane & 15)][kc * 32 + (lane >> 4) * 8];
  const unsigned short* Wf[3] = {Wqf, Wkf, Wvf};
  const float* bias[3] = {bq, bk, bv};
#pragma unroll
  for (int mm = 0; mm < 3; mm++) {
    const unsigned short* wf = Wf[mm];
    float bscale = (mm == 0) ? 0.25f : 1.0f;   // Wq pre-scaled by 0.25; scale bq to match
    for (int ct = 0; ct < 8; ct++) {
      floatx4 acc = {0.f, 0.f, 0.f, 0.f};
#pragma unroll
      for (int kc = 0; kc < 4; kc++) {
        short8 b = *(const short8*)(wf + ((size_t)(ct * 4 + kc) * 64 + lane) * 8);
        acc = __builtin_amdgcn_mfma_f32_16x16x32_bf16(a[kc], b, acc, 0, 0, 0);
      }
      int col = ct * 16 + (lane & 15);
      float bb = bias[mm][col] * bscale;
#pragma unroll
      for (int r = 0; r < 4; r++) {
        int rr = r0 + (lane >> 4) * 4 + r;
        int nd = n0 + rr;
        if (nd < NN) {
          float val = acc[r] + bb;
          if (mm == 0) q[(size_t)nd * HDIM + col] = f2bf(val);
          else if (mm == 1) kf8[(size_t)nd * HDIM + col] = f2fp8(val);
          else vf8[(size_t)nd * HDIM + col] = f2fp8(val);
        }
      }
    }
  }
}

// ---------------- attention: one 16-lane group per node, depth-4, fp8 K+V ----------------
__global__ __launch_bounds__(256) void k_attn(
    const unsigned short* __restrict__ q, const unsigned char* __restrict__ kf8,
    const unsigned char* __restrict__ vf8,
    const int* __restrict__ cols, const unsigned short* __restrict__ ebias,
    const int* __restrict__ starts,
    unsigned short* __restrict__ out) {
  int t = threadIdx.x;
  int wave = t >> 6, lane = t & 63;
  int g = lane >> 4, d = lane & 15;
  int node = blockIdx.x * 16 + wave * 4 + g;
  if (node >= NN) return;
  int hh = d >> 1;                      // head owned by this lane

  float qf[8];
  {
    ushort8 q8 = *(const ushort8*)(q + (size_t)node * HDIM + d * 8);
#pragma unroll
    for (int j = 0; j < 8; j++) qf[j] = bf2f(q8[j]);   // 0.25 scale pre-folded
  }

  int s0 = starts[node], s1 = starts[node + 1];
  float acc[8];
#pragma unroll
  for (int j = 0; j < 8; j++) acc[j] = 0.f;
  float lsum = 0.f;

  // depth-4 slots: data (k fp8, v fp8, bias) + pending (col, bias) for next edge
  uint2 sk[4], sv[4];
  float seb[4];
  int pc[4];
  float peb[4];

#pragma unroll
  for (int j = 0; j < 4; j++) {
    int i = s0 + j;
    bool ok = i < s1;
    int c = ok ? cols[i] : 0;
    sk[j] = *(const uint2*)(kf8 + (size_t)c * HDIM + d * 8);
    sv[j] = *(const uint2*)(vf8 + (size_t)c * HDIM + d * 8);
    seb[j] = ok ? bf2f(ebias[(size_t)i * 8 + hh]) : -1e30f;
  }
#pragma unroll
  for (int j = 0; j < 4; j++) {
    int i = s0 + 4 + j;
    bool ok = i < s1;
    pc[j] = ok ? cols[i] : 0;
    peb[j] = ok ? bf2f(ebias[(size_t)i * 8 + hh]) : -1e30f;
  }

  for (int base = s0; base < s1; base += 4) {
#pragma unroll
    for (int j = 0; j < 4; j++) {
      // stage data for edge (base+4+j)
      int c = pc[j];
      uint2 kn = *(const uint2*)(kf8 + (size_t)c * HDIM + d * 8);
      uint2 vn = *(const uint2*)(vf8 + (size_t)c * HDIM + d * 8);
      float ebn = peb[j];
      // stage ids/bias for edge (base+8+j)
      int i2 = base + 8 + j;
      bool ok2 = i2 < s1;
      int c2 = ok2 ? cols[i2] : 0;
      float eb2 = ok2 ? bf2f(ebias[(size_t)i2 * 8 + hh]) : -1e30f;
      // compute current slot j (edge base+j); invalid -> seb=-1e30 -> ex=0
      float kf[8], vf[8];
      fp8x8_dec(sk[j], kf);
      fp8x8_dec(sv[j], vf);
      float part = 0.f;
#pragma unroll
      for (int u = 0; u < 8; u++) part += qf[u] * kf[u];
      part += __shfl_xor(part, 1);
      float ex = __expf(part + seb[j]);
      lsum += ex;
#pragma unroll
      for (int u = 0; u < 8; u++) acc[u] += ex * vf[u];
      // rotate
      sk[j] = kn; sv[j] = vn; seb[j] = ebn;
      pc[j] = c2; peb[j] = eb2;
    }
  }

  float inv = 1.f / (lsum + 1e-10f);
  ushort8 o;
#pragma unroll
  for (int j = 0; j < 8; j++) o[j] = f2bf(acc[j] * inv);
  *(ushort8*)(out + (size_t)node * HDIM + d * 8) = o;
}

// ------- mega-fused: oproj + residual + LN2 + FFN + residual [+ LN1'+QKV' of next layer]
// Body of the proven round-10 kernel, plus an appended phase that is a VERBATIM copy of
// k_ln_qkv_mfma's math on this block's 32 rows (reads the just-written fp32 x from global
// after a barrier -> bit-identical q/kf8/vf8 to the standalone kernel).
__global__ __launch_bounds__(256) void k_oproj_ffn_qkv(
    const unsigned short* __restrict__ ao, const unsigned short* __restrict__ Wof,
    const float* __restrict__ bo,
    const unsigned short* __restrict__ W1f, const float* __restrict__ b1,
    const unsigned short* __restrict__ W2f, const float* __restrict__ b2,
    const float* __restrict__ g, const float* __restrict__ be,
    float* __restrict__ x,
    int doQKV,
    const unsigned short* __restrict__ WqfN, const float* __restrict__ bqN,
    const unsigned short* __restrict__ WkfN, const float* __restrict__ bkN,
    const unsigned short* __restrict__ WvfN, const float* __restrict__ bvN,
    const float* __restrict__ gN, const float* __restrict__ beN,
    unsigned short* __restrict__ qOut, unsigned char* __restrict__ kf8Out,
    unsigned char* __restrict__ vf8Out) {
  __shared__ unsigned short pool[32 * 536];        // 34304 B
  unsigned short* aosp = pool;                     // [row*136+col]
  float* xrp = (float*)(pool + 8704);              // [row*132+col], 16896 B
  unsigned short* xnp = pool;                      // reuses aos region
  int t = threadIdx.x;
  int n0 = blockIdx.x * 32;

  // Stage A: load ao tile (bf16, coalesced) and x tile (fp32, coalesced)
#pragma unroll
  for (int c = 0; c < 2; c++) {
    int elem = c * 2048 + t * 8;
    int row = elem >> 7, col = elem & 127;
    int nd = n0 + row;
    ushort8 u = {0, 0, 0, 0, 0, 0, 0, 0};
    if (nd < NN) u = *(const ushort8*)(ao + (size_t)nd * HDIM + col);
    *(ushort8*)&aosp[row * 136 + col] = u;
  }
#pragma unroll
  for (int c = 0; c < 4; c++) {
    int elem = c * 1024 + t * 4;
    int row = elem >> 7, col = elem & 127;
    int nd = n0 + row;
    float4 f = {0.f, 0.f, 0.f, 0.f};
    if (nd < NN) f = *(const float4*)(x + (size_t)nd * HDIM + col);
    *(float4*)&xrp[row * 132 + col] = f;
  }
  __syncthreads();

  int w = t >> 6, lane = t & 63;
  int rt = w & 1, r0 = rt * 16;
  int cthalf = w >> 1;
  int lcol = lane & 15, lrow8 = (lane >> 4) * 8, lrow4 = (lane >> 4) * 4;

  // oproj: racc = x + ao @ Wo + bo  (kept in regs, C layout) ; also written to xr for LN
  float racc[4][4];
  {
    short8 a[4];
#pragma unroll
    for (int kc = 0; kc < 4; kc++)
      a[kc] = *(const short8*)&aosp[(r0 + lcol) * 136 + kc * 32 + lrow8];
#pragma unroll
    for (int ci = 0; ci < 4; ci++) {
      int ct = cthalf * 4 + ci;
      floatx4 acc = {0.f, 0.f, 0.f, 0.f};
#pragma unroll
      for (int kc = 0; kc < 4; kc++) {
        short8 b = *(const short8*)(Wof + ((size_t)(ct * 4 + kc) * 64 + lane) * 8);
        acc = __builtin_amdgcn_mfma_f32_16x16x32_bf16(a[kc], b, acc, 0, 0, 0);
      }
      int col = ct * 16 + lcol;
      float bb = bo[col];
#pragma unroll
      for (int r = 0; r < 4; r++) {
        int rr = r0 + lrow4 + r;
        float v = xrp[rr * 132 + col] + acc[r] + bb;
        racc[ci][r] = v;
        xrp[rr * 132 + col] = v;
      }
    }
  }
  __syncthreads();

  // LN2 from xr -> xn at pool offset 0 (aos dead); 8 lanes/row
  {
    int row = t >> 3, oct = t & 7;
    float xv[16];
    float s = 0.f, sq = 0.f;
#pragma unroll
    for (int jj = 0; jj < 16; jj++) {
      float f = xrp[row * 132 + oct * 16 + jj];
      xv[jj] = f; s += f; sq += f * f;
    }
    s += __shfl_xor(s, 1); s += __shfl_xor(s, 2); s += __shfl_xor(s, 4);
    sq += __shfl_xor(sq, 1); sq += __shfl_xor(sq, 2); sq += __shfl_xor(sq, 4);
    float m = s * (1.f / HDIM);
    float rv = rsqrtf(sq * (1.f / HDIM) - m * m + 1e-5f);
#pragma unroll
    for (int cb = 0; cb < 2; cb++) {
      ushort8 u;
#pragma unroll
      for (int jj = 0; jj < 8; jj++) {
        int col = oct * 16 + cb * 8 + jj;
        u[jj] = f2bf((xv[cb*8+jj] - m) * rv * g[col] + be[col]);
      }
      *(ushort8*)&xnp[row * 136 + oct * 16 + cb * 8] = u;
    }
  }
  __syncthreads();

  // load GEMM1 A-fragments from xn BEFORE the pool is overwritten by hs
  short8 axn[4];
#pragma unroll
  for (int kc = 0; kc < 4; kc++)
    axn[kc] = *(const short8*)&xnp[(r0 + lcol) * 136 + kc * 32 + lrow8];
  __syncthreads();   // all xn reads done; pool free for hidden

  // GEMM1: hidden = relu(xn @ W1 + b1) -> pool rows stride 536
  for (int ci = 0; ci < 16; ci++) {
    int ct = cthalf * 16 + ci;
    floatx4 acc = {0.f, 0.f, 0.f, 0.f};
#pragma unroll
    for (int kc = 0; kc < 4; kc++) {
      short8 b = *(const short8*)(W1f + ((size_t)(ct * 4 + kc) * 64 + lane) * 8);
      acc = __builtin_amdgcn_mfma_f32_16x16x32_bf16(axn[kc], b, acc, 0, 0, 0);
    }
    int col = ct * 16 + lcol;
    float bb = b1[col];
#pragma unroll
    for (int r = 0; r < 4; r++) {
      pool[(r0 + lrow4 + r) * 536 + col] = f2bf(fmaxf(acc[r] + bb, 0.f));
    }
  }
  __syncthreads();

  // GEMM2: x = hidden @ W2 + b2 + racc
  {
    short8 ah[16];
#pragma unroll
    for (int kc = 0; kc < 16; kc++)
      ah[kc] = *(const short8*)&pool[(r0 + lcol) * 536 + kc * 32 + lrow8];
#pragma unroll
    for (int ci = 0; ci < 4; ci++) {
      int ct2 = cthalf * 4 + ci;
      floatx4 acc = {0.f, 0.f, 0.f, 0.f};
#pragma unroll
      for (int kc = 0; kc < 16; kc++) {
        short8 b = *(const short8*)(W2f + ((size_t)(ct2 * 16 + kc) * 64 + lane) * 8);
        acc = __builtin_amdgcn_mfma_f32_16x16x32_bf16(ah[kc], b, acc, 0, 0, 0);
      }
      int col = ct2 * 16 + lcol;
      float bb = b2[col];
#pragma unroll
      for (int r = 0; r < 4; r++) {
        int nd = n0 + r0 + lrow4 + r;
        if (nd < NN) x[(size_t)nd * HDIM + col] = racc[ci][r] + acc[r] + bb;
      }
    }
  }

  if (!doQKV) return;
  // barrier drains the global x stores (vmcnt(0) before s_barrier) and the pool reads
  __syncthreads();

  // ---- LN1 of NEXT layer: verbatim k_ln_qkv_mfma math on this block's 32 rows ----
  if (t < 128) {
    int row = t >> 2, quad = t & 3;   // 4 lanes/row, 32 elems each (rows 0..31)
    int node = n0 + row;
    float xv[32];
    float s = 0.f, sq = 0.f;
    if (node < NN) {
      const float* xr = x + (size_t)node * HDIM + quad * 32;
#pragma unroll
      for (int c = 0; c < 8; c++) {
        float4 f = *(const float4*)(xr + c * 4);
        xv[c*4+0]=f.x; xv[c*4+1]=f.y; xv[c*4+2]=f.z; xv[c*4+3]=f.w;
      }
#pragma unroll
      for (int j = 0; j < 32; j++) { s += xv[j]; sq += xv[j]*xv[j]; }
    } else {
#pragma unroll
      for (int j = 0; j < 32; j++) xv[j] = 0.f;
    }
    s += __shfl_xor(s, 1); s += __shfl_xor(s, 2);
    sq += __shfl_xor(sq, 1); sq += __shfl_xor(sq, 2);
    float m = s * (1.f / HDIM);
    float rv = rsqrtf(sq * (1.f / HDIM) - m * m + 1e-5f);
#pragma unroll
    for (int cb = 0; cb < 4; cb++) {
      ushort8 u;
#pragma unroll
      for (int j = 0; j < 8; j++) {
        int col = quad * 32 + cb * 8 + j;
        u[j] = f2bf((xv[cb*8+j] - m) * rv * gN[col] + beN[col]);
      }
      *(ushort8*)&xnp[row * 136 + quad * 32 + cb * 8] = u;
    }
  }
  __syncthreads();

  // ---- QKV GEMMs for next layer: wave (rt,cthalf) -> rows r0..r0+15, ct = cthalf*4+ci ----
  {
    short8 a2[4];
#pragma unroll
    for (int kc = 0; kc < 4; kc++)
      a2[kc] = *(const short8*)&xnp[(r0 + lcol) * 136 + kc * 32 + lrow8];
    const unsigned short* Wf[3] = {WqfN, WkfN, WvfN};
    const float* bias[3] = {bqN, bkN, bvN};
#pragma unroll
    for (int mm = 0; mm < 3; mm++) {
      const unsigned short* wf = Wf[mm];
      float bscale = (mm == 0) ? 0.25f : 1.0f;
#pragma unroll
      for (int ci = 0; ci < 4; ci++) {
        int ct = cthalf * 4 + ci;
        floatx4 acc = {0.f, 0.f, 0.f, 0.f};
#pragma unroll
        for (int kc = 0; kc < 4; kc++) {
          short8 b = *(const short8*)(wf + ((size_t)(ct * 4 + kc) * 64 + lane) * 8);
          acc = __builtin_amdgcn_mfma_f32_16x16x32_bf16(a2[kc], b, acc, 0, 0, 0);
        }
        int col = ct * 16 + lcol;
        float bb = bias[mm][col] * bscale;
#pragma unroll
        for (int r = 0; r < 4; r++) {
          int nd = n0 + r0 + lrow4 + r;
          if (nd < NN) {
            float val = acc[r] + bb;
            if (mm == 0) qOut[(size_t)nd * HDIM + col] = f2bf(val);
            else if (mm == 1) kf8Out[(size_t)nd * HDIM + col] = f2fp8(val);
            else vf8Out[(size_t)nd * HDIM + col] = f2fp8(val);
          }
        }
      }
    }
  }
}

// ---------------- final LN -> d_out (vectorized, 64 nodes/block) ----------------
__global__ __launch_bounds__(256) void k_final(
    const float* __restrict__ x, const float* __restrict__ g,
    const float* __restrict__ be, float* __restrict__ outx) {
  int t = threadIdx.x;
  int row = t >> 2, quad = t & 3;      // 4 lanes/row, 32 elems each
  int node = blockIdx.x * 64 + row;
  if (node >= NN) return;
  const float* xr = x + (size_t)node * HDIM + quad * 32;
  float xv[32];
  float s = 0.f, sq = 0.f;
#pragma unroll
  for (int c = 0; c < 8; c++) {
    float4 f = *(const float4*)(xr + c * 4);
    xv[c*4+0]=f.x; xv[c*4+1]=f.y; xv[c*4+2]=f.z; xv[c*4+3]=f.w;
  }
#pragma unroll
  for (int j = 0; j < 32; j++) { s += xv[j]; sq += xv[j]*xv[j]; }
  s += __shfl_xor(s, 1); s += __shfl_xor(s, 2);
  sq += __shfl_xor(sq, 1); sq += __shfl_xor(sq, 2);
  float m = s * (1.f / HDIM);
  float rv = rsqrtf(sq * (1.f / HDIM) - m * m + 1e-5f);
  float* orow = outx + (size_t)node * HDIM + quad * 32;
#pragma unroll
  for (int c = 0; c < 8; c++) {
    float4 o;
    int col = quad * 32 + c * 4;
    o.x = (xv[c*4+0] - m) * rv * g[col+0] + be[col+0];
    o.y = (xv[c*4+1] - m) * rv * g[col+1] + be[col+1];
    o.z = (xv[c*4+2] - m) * rv * g[col+2] + be[col+2];
    o.w = (xv[c*4+3] - m) * rv * g[col+3] + be[col+3];
    *(float4*)(orow + c * 4) = o;
  }
}

// ---------------- graph mean pooling (batch is sorted; counts from gstart) ----------------
__global__ void k_pool(const float* __restrict__ outx, const int* __restrict__ gstart,
                       float* __restrict__ outg) {
  __shared__ float part[4][HDIM];
  int g = blockIdx.x;
  int t = threadIdx.x;  // 512
  int hd = t & 127, p = t >> 7;
  int s0 = gstart[g];
  int c = gstart[g + 1] - s0;
  float s = 0.f;
  for (int i = p; i < c; i += 4) s += outx[(size_t)(s0 + i) * HDIM + hd];
  part[p][hd] = s;
  __syncthreads();
  if (p == 0) {
    float tot = part[0][hd] + part[1][hd] + part[2][hd] + part[3][hd];
    outg[g * HDIM + hd] = tot / fmaxf((float)c, 1.f);
  }
}

extern "C" void kernel_launch(void* const* d_in, const int* in_sizes, int n_in,
                              void* d_out, int out_size, void* d_ws, size_t ws_size,
                              hipStream_t stream) {
  const float* h      = (const float*)d_in[0];
  const float* e      = (const float*)d_in[1];
  const int*   eidx   = (const int*)d_in[2];
  const int*   batch  = (const int*)d_in[3];
  const float* node_W = (const float*)d_in[4];
  const float* node_b = (const float*)d_in[5];
  const float* edge_W = (const float*)d_in[6];
  const float* edge_b = (const float*)d_in[7];
  const float* Wq  = (const float*)d_in[8];
  const float* bq  = (const float*)d_in[9];
  const float* Wk  = (const float*)d_in[10];
  const float* bk  = (const float*)d_in[11];
  const float* Wv  = (const float*)d_in[12];
  const float* bv  = (const float*)d_in[13];
  const float* Wo  = (const float*)d_in[14];
  const float* bo  = (const float*)d_in[15];
  const float* Web = (const float*)d_in[16];
  const float* beb = (const float*)d_in[17];
  const float* W1  = (const float*)d_in[18];
  const float* b1  = (const float*)d_in[19];
  const float* W2  = (const float*)d_in[20];
  const float* b2  = (const float*)d_in[21];
  const float* g1  = (const float*)d_in[22];
  const float* be1 = (const float*)d_in[23];
  const float* g2  = (const float*)d_in[24];
  const float* be2 = (const float*)d_in[25];
  const float* gF  = (const float*)d_in[26];
  const float* bF  = (const float*)d_in[27];

  const int* rowArr = eidx;
  const int* colArr = eidx + EE;

  char* ws = (char*)d_ws;
  size_t off = 0;
  auto alloc = [&](size_t bytes) -> void* {
    void* p = ws + off;
    off = (off + bytes + 255) & ~(size_t)255;
    return p;
  };
  float* x    = (float*)alloc((size_t)NN * HDIM * 4);
  unsigned short* qb  = (unsigned short*)alloc((size_t)NN * HDIM * 2);
  unsigned char*  kf8 = (unsigned char*)alloc((size_t)NN * HDIM);
  unsigned char*  vf8 = (unsigned char*)alloc((size_t)NN * HDIM);
  unsigned short* ao  = (unsigned short*)alloc((size_t)NN * HDIM * 2);
  int* deg    = (int*)alloc((size_t)NN * 4);
  int* starts = (int*)alloc((size_t)(NN + 1) * 4);
  int* cursor = (int*)alloc((size_t)NN * 4);
  int* eids   = (int*)alloc((size_t)EE * 4);
  int* cols   = (int*)alloc((size_t)EE * 4);
  unsigned short* ebias = (unsigned short*)alloc((size_t)EE * HH * 2);
  int* bsum   = (int*)alloc((size_t)SCB * 4);
  float* Wcomb = (float*)alloc((size_t)LL * EDI * HH * 4);
  float* bcomb = (float*)alloc((size_t)LL * HH * 4);
  int* gstart = (int*)alloc((size_t)(GG + 1) * 4);
  // fragment-packed bf16 weights
  const int QKV_FRAG = 8 * 4 * 512;    // 16384 elems per matrix per layer
  const int FFN_FRAG1 = 32 * 4 * 512;  // 65536
  const int FFN_FRAG2 = 8 * 16 * 512;  // 65536
  unsigned short* Wqf = (unsigned short*)alloc((size_t)LL * QKV_FRAG * 2);
  unsigned short* Wkf = (unsigned short*)alloc((size_t)LL * QKV_FRAG * 2);
  unsigned short* Wvf = (unsigned short*)alloc((size_t)LL * QKV_FRAG * 2);
  unsigned short* Wof = (unsigned short*)alloc((size_t)LL * QKV_FRAG * 2);
  unsigned short* W1f = (unsigned short*)alloc((size_t)LL * FFN_FRAG1 * 2);
  unsigned short* W2f = (unsigned short*)alloc((size_t)LL * FFN_FRAG2 * 2);

  // all-layers ebias if workspace permits (deterministic: depends only on ws_size)
  size_t need6 = (size_t)LL * EE * HH * 2;
  unsigned short* ebias6 = nullptr;
  if (off + need6 + 256 <= ws_size) ebias6 = (unsigned short*)alloc(need6);

  hipMemsetAsync(deg, 0, (size_t)NN * 4, stream);

  k_node_proj<<<(NN + 31) / 32, 128, 0, stream>>>(h, node_W, node_b, x);
  k_wcomb<<<1, 256, 0, stream>>>(edge_W, edge_b, Web, beb, Wcomb, bcomb);
  k_pack<<<(LL * QKV_FRAG + 255) / 256, 256, 0, stream>>>(Wq, Wqf, HDIM, HDIM, LL, 0.25f);
  k_pack<<<(LL * QKV_FRAG + 255) / 256, 256, 0, stream>>>(Wk, Wkf, HDIM, HDIM, LL, 1.0f);
  k_pack<<<(LL * QKV_FRAG + 255) / 256, 256, 0, stream>>>(Wv, Wvf, HDIM, HDIM, LL, 1.0f);
  k_pack<<<(LL * QKV_FRAG + 255) / 256, 256, 0, stream>>>(Wo, Wof, HDIM, HDIM, LL, 1.0f);
  k_pack<<<(LL * FFN_FRAG1 + 255) / 256, 256, 0, stream>>>(W1, W1f, HDIM, FFD, LL, 1.0f);
  k_pack<<<(LL * FFN_FRAG2 + 255) / 256, 256, 0, stream>>>(W2, W2f, FFD, HDIM, LL, 1.0f);
  k_deg<<<(EE + 255) / 256, 256, 0, stream>>>(rowArr, deg);
  k_scan1<<<SCB, 256, 0, stream>>>(deg, bsum);
  k_scan2<<<1, 64, 0, stream>>>(bsum, starts);
  k_scan3<<<SCB, 256, 0, stream>>>(deg, bsum, starts, cursor);
  k_scatter<<<(EE + 255) / 256, 256, 0, stream>>>(rowArr, colArr, cursor, eids, cols);
  k_gbounds<<<(NN + 255) / 256, 256, 0, stream>>>(batch, gstart);

  int nb64 = (NN + 63) / 64;
  int nb32 = (NN + 31) / 32;
  int nb16 = (NN + 15) / 16;
  int nbE  = (EE + 255) / 256;

  if (ebias6) {
    k_ebias_all<<<nbE, 256, 0, stream>>>(eids, e, Wcomb, bcomb, ebias6);
  }

  // layer 0 QKV (standalone); layers 1..5 QKV fused into previous layer's epilogue
  k_ln_qkv_mfma<<<nb64, 256, 0, stream>>>(x,
      Wqf, bq, Wkf, bk, Wvf, bv, g1, be1, qb, kf8, vf8);

  for (int l = 0; l < LL; l++) {
    const unsigned short* eb_l;
    if (ebias6) {
      eb_l = ebias6 + (size_t)l * EE * HH;
    } else {
      k_ebias<<<nbE, 256, 0, stream>>>(eids, e,
          Wcomb + (size_t)l * EDI * HH, bcomb + (size_t)l * HH, ebias);
      eb_l = ebias;
    }
    k_attn<<<nb16, 256, 0, stream>>>(qb, kf8, vf8, cols, eb_l, starts, ao);
    int ln = (l < LL - 1) ? (l + 1) : l;     // next-layer weights (unused when doQKV=0)
    k_oproj_ffn_qkv<<<nb32, 256, 0, stream>>>(ao, Wof + (size_t)l * QKV_FRAG,
        bo + (size_t)l * HDIM,
        W1f + (size_t)l * FFN_FRAG1, b1 + (size_t)l * FFD,
        W2f + (size_t)l * FFN_FRAG2, b2 + (size_t)l * HDIM,
        g2 + (size_t)l * HDIM, be2 + (size_t)l * HDIM, x,
        (l < LL - 1) ? 1 : 0,
        Wqf + (size_t)ln * QKV_FRAG, bq + (size_t)ln * HDIM,
        Wkf + (size_t)ln * QKV_FRAG, bk + (size_t)ln * HDIM,
        Wvf + (size_t)ln * QKV_FRAG, bv + (size_t)ln * HDIM,
        g1 + (size_t)ln * HDIM, be1 + (size_t)ln * HDIM,
        qb, kf8, vf8);
  }

  float* outx = (float*)d_out;
  float* outg = outx + (size_t)NN * HDIM;
  k_final<<<(NN + 63) / 64, 256, 0, stream>>>(x, gF, bF, outx);
  k_pool<<<GG, 512, 0, stream>>>(outx, gstart, outg);
}

// Round 15
// 1071.204 us; speedup vs baseline: 1.1437x; 1.1437x over previous
//
#include <hip/hip_runtime.h>
#include <hip/hip_bf16.h>
#include <math.h>

#define NN 50000
#define EE 800000
#define HH 8
#define DD 16
#define HDIM 128
#define LL 6
#define GG 64
#define NDI 48
#define EDI 4
#define FFD 512
#define SCB ((NN + 1023) / 1024)   // scan blocks = 49

typedef __attribute__((ext_vector_type(8))) short short8;
typedef __attribute__((ext_vector_type(8))) unsigned short ushort8;
typedef __attribute__((ext_vector_type(4))) float floatx4;
typedef __attribute__((ext_vector_type(2))) float f32x2;

__device__ __forceinline__ unsigned short f2bf(float f) {
  unsigned u = __builtin_bit_cast(unsigned, f);
  unsigned rnd = 0x7FFFu + ((u >> 16) & 1u);
  return (unsigned short)((u + rnd) >> 16);
}
__device__ __forceinline__ float bf2f(unsigned short u) {
  unsigned v = ((unsigned)u) << 16;
  return __builtin_bit_cast(float, v);
}

#ifdef __has_builtin
#if __has_builtin(__builtin_amdgcn_cvt_pk_f32_fp8) && __has_builtin(__builtin_amdgcn_cvt_pk_fp8_f32)
#define HW_FP8 1
#endif
#endif

// e4m3 encode (single value)
__device__ __forceinline__ unsigned char f2fp8(float f) {
#ifdef HW_FP8
  int p = __builtin_amdgcn_cvt_pk_fp8_f32(f, 0.f, 0, false);
  return (unsigned char)(p & 0xff);
#else
  unsigned u = __builtin_bit_cast(unsigned, f);
  unsigned s = (u >> 24) & 0x80u;
  unsigned au = u & 0x7fffffffu;
  float a = __builtin_bit_cast(float, au);
  if (a >= 448.f) return (unsigned char)(s | 0x7e);
  if (a < 0.0009765625f) return (unsigned char)s;  // < 2^-10 -> 0
  int e32 = (int)(au >> 23) - 127;
  if (e32 >= -6) {
    au += (1u << 19);  // round-to-nearest (half ulp of 3-bit mantissa)
    e32 = (int)(au >> 23) - 127;
    if (e32 > 8) return (unsigned char)(s | 0x7e);
    unsigned m = (au >> 20) & 7u;
    return (unsigned char)(s | (unsigned)((e32 + 7) << 3) | m);
  } else {
    int m = (int)(a * 512.f + 0.5f);
    if (m > 7) return (unsigned char)(s | 0x08);
    return (unsigned char)(s | (unsigned)m);
  }
#endif
}

// decode 8 fp8 (uint2) -> float[8]
__device__ __forceinline__ void fp8x8_dec(uint2 kw, float* f) {
#ifdef HW_FP8
  f32x2 a = __builtin_amdgcn_cvt_pk_f32_fp8((int)kw.x, false);
  f32x2 b = __builtin_amdgcn_cvt_pk_f32_fp8((int)kw.x, true);
  f32x2 c = __builtin_amdgcn_cvt_pk_f32_fp8((int)kw.y, false);
  f32x2 d = __builtin_amdgcn_cvt_pk_f32_fp8((int)kw.y, true);
  f[0] = a[0]; f[1] = a[1]; f[2] = b[0]; f[3] = b[1];
  f[4] = c[0]; f[5] = c[1]; f[6] = d[0]; f[7] = d[1];
#else
  unsigned w[2] = {kw.x, kw.y};
#pragma unroll
  for (int i = 0; i < 8; i++) {
    unsigned char bb = (unsigned char)((w[i >> 2] >> ((i & 3) * 8)) & 0xff);
    unsigned s = ((unsigned)bb & 0x80u) << 24;
    unsigned e = (bb >> 3) & 0xFu;
    unsigned m = bb & 7u;
    float v;
    if (e == 0) v = (float)m * 0.001953125f;
    else v = __builtin_bit_cast(float, ((e + 120u) << 23) | (m << 20));
    f[i] = __builtin_bit_cast(float, __builtin_bit_cast(unsigned, v) | s);
  }
#endif
}

// ---------------- node input projection: x = h @ node_W + node_b (fp32) ----------------
__global__ void k_node_proj(const float* __restrict__ h, const float* __restrict__ W,
                            const float* __restrict__ b, float* __restrict__ x) {
  __shared__ float hs[32][NDI];
  int t = threadIdx.x;                 // 128
  int n0 = blockIdx.x * 32;
  for (int idx = t; idx < 32 * NDI; idx += 128) {
    int nb = idx / NDI, i = idx - nb * NDI;
    int node = n0 + nb;
    hs[nb][i] = (node < NN) ? h[node * NDI + i] : 0.f;
  }
  __syncthreads();
  float acc[32];
#pragma unroll
  for (int nb = 0; nb < 32; nb++) acc[nb] = 0.f;
  for (int i = 0; i < NDI; i++) {
    float w = W[i * HDIM + t];
#pragma unroll
    for (int nb = 0; nb < 32; nb++) acc[nb] += hs[nb][i] * w;
  }
  float bb = b[t];
  for (int nb = 0; nb < 32; nb++) {
    int node = n0 + nb;
    if (node < NN) x[node * HDIM + t] = acc[nb] + bb;
  }
}

// ------- single-launch weight fragment pre-pack for all 6 matrices -------
// Element mapping identical to the per-matrix k_pack (bit-identical outputs).
#define QKV_TOT (LL * 8 * 4 * 512)    // 98304 per matrix
#define FFN1_TOT (LL * 32 * 4 * 512)  // 393216
#define FFN2_TOT (LL * 8 * 16 * 512)  // 393216
#define PACK_TOT (4 * QKV_TOT + FFN1_TOT + FFN2_TOT)

__global__ void k_pack_all(
    const float* __restrict__ Wq, const float* __restrict__ Wk,
    const float* __restrict__ Wv, const float* __restrict__ Wo,
    const float* __restrict__ W1, const float* __restrict__ W2,
    unsigned short* __restrict__ Wqf, unsigned short* __restrict__ Wkf,
    unsigned short* __restrict__ Wvf, unsigned short* __restrict__ Wof,
    unsigned short* __restrict__ W1f, unsigned short* __restrict__ W2f) {
  for (int i = blockIdx.x * 256 + threadIdx.x; i < PACK_TOT; i += gridDim.x * 256) {
    const float* W; unsigned short* dst; int K, OC; float scale = 1.0f;
    int idx = i;
    if (idx < QKV_TOT) { W = Wq; dst = Wqf; K = HDIM; OC = HDIM; scale = 0.25f; }
    else if (idx < 2 * QKV_TOT) { idx -= QKV_TOT; W = Wk; dst = Wkf; K = HDIM; OC = HDIM; }
    else if (idx < 3 * QKV_TOT) { idx -= 2 * QKV_TOT; W = Wv; dst = Wvf; K = HDIM; OC = HDIM; }
    else if (idx < 4 * QKV_TOT) { idx -= 3 * QKV_TOT; W = Wo; dst = Wof; K = HDIM; OC = HDIM; }
    else if (idx < 4 * QKV_TOT + FFN1_TOT) { idx -= 4 * QKV_TOT; W = W1; dst = W1f; K = HDIM; OC = FFD; }
    else { idx -= 4 * QKV_TOT + FFN1_TOT; W = W2; dst = W2f; K = FFD; OC = HDIM; }
    int KC = K >> 5, CT = OC >> 4;
    int j = idx & 7;
    int lane = (idx >> 3) & 63;
    int rest = idx >> 9;
    int kc = rest % KC; rest /= KC;
    int ct = rest % CT; int m = rest / CT;
    int col = ct * 16 + (lane & 15);
    int k = kc * 32 + (lane >> 4) * 8 + j;
    dst[idx] = f2bf(scale * W[(size_t)m * K * OC + (size_t)k * OC + col]);
  }
}

// ------- combined edge-bias matrices: Wcomb[l] = edge_W @ Web[l]  [4x8], bcomb -------
__global__ void k_wcomb(const float* __restrict__ edge_W, const float* __restrict__ edge_b,
                        const float* __restrict__ Web, const float* __restrict__ beb,
                        float* __restrict__ Wcomb, float* __restrict__ bcomb) {
  int t = threadIdx.x;  // 256
  if (t < LL * EDI * HH) {  // 192
    int l = t / (EDI * HH);
    int i = (t / HH) % EDI;
    int hh = t % HH;
    float s = 0.f;
    for (int j = 0; j < HDIM; j++) s += edge_W[i * HDIM + j] * Web[(l * HDIM + j) * HH + hh];
    Wcomb[t] = s;
  } else if (t < LL * EDI * HH + LL * HH) {  // next 48
    int u = t - LL * EDI * HH;
    int l = u / HH, hh = u % HH;
    float s = beb[l * HH + hh];
    for (int j = 0; j < HDIM; j++) s += edge_b[j] * Web[(l * HDIM + j) * HH + hh];
    bcomb[u] = s;
  }
}

// ---------------- CSR build ----------------
__global__ void k_deg(const int* __restrict__ row, int* __restrict__ deg) {
  int e = blockIdx.x * 256 + threadIdx.x;
  if (e < EE) atomicAdd(&deg[row[e]], 1);
}

__global__ void k_scan1(const int* __restrict__ deg, int* __restrict__ bsum) {
  __shared__ int red[256];
  int b = blockIdx.x, t = threadIdx.x;
  int base = b * 1024;
  int s = 0;
  for (int j = t; j < 1024; j += 256) {
    int i = base + j;
    s += (i < NN) ? deg[i] : 0;
  }
  red[t] = s;
  __syncthreads();
  for (int off = 128; off > 0; off >>= 1) {
    if (t < off) red[t] += red[t + off];
    __syncthreads();
  }
  if (t == 0) bsum[b] = red[0];
}

__global__ void k_scan2(int* __restrict__ bsum, int* __restrict__ starts) {
  if (threadIdx.x == 0) {
    int s = 0;
    for (int b = 0; b < SCB; b++) { int v = bsum[b]; bsum[b] = s; s += v; }
    starts[NN] = s;
  }
}

__global__ void k_scan3(const int* __restrict__ deg, const int* __restrict__ bsum,
                        int* __restrict__ starts, int* __restrict__ cursor) {
  __shared__ int tsum[256];
  int b = blockIdx.x, t = threadIdx.x;
  int base = b * 1024 + t * 4;
  int v[4];
  int s = 0;
#pragma unroll
  for (int j = 0; j < 4; j++) {
    int i = base + j;
    v[j] = (i < NN) ? deg[i] : 0;
    s += v[j];
  }
  tsum[t] = s;
  __syncthreads();
  for (int off = 1; off < 256; off <<= 1) {
    int xv = (t >= off) ? tsum[t - off] : 0;
    __syncthreads();
    tsum[t] += xv;
    __syncthreads();
  }
  int excl = tsum[t] - s + bsum[b];
#pragma unroll
  for (int j = 0; j < 4; j++) {
    int i = base + j;
    if (i < NN) { starts[i] = excl; cursor[i] = excl; excl += v[j]; }
  }
}

// scatter writes CSR edge ids AND direct column ids
__global__ void k_scatter(const int* __restrict__ row, const int* __restrict__ col,
                          int* __restrict__ cursor,
                          int* __restrict__ eids, int* __restrict__ cols) {
  int e = blockIdx.x * 256 + threadIdx.x;
  if (e < EE) {
    int r = row[e];
    int pos = atomicAdd(&cursor[r], 1);
    eids[pos] = e;
    cols[pos] = col[e];
  }
}

// ---------------- graph ranges from sorted batch: boundary detection ----------------
__global__ void k_gbounds(const int* __restrict__ batch, int* __restrict__ gstart) {
  int i = blockIdx.x * 256 + threadIdx.x;
  if (i >= NN) return;
  int b = batch[i];
  int prev = (i == 0) ? -1 : batch[i - 1];
  for (int g = prev + 1; g <= b; g++) gstart[g] = i;
  if (i == NN - 1) {
    for (int g = b + 1; g <= GG; g++) gstart[g] = NN;
  }
}

// ---------------- per-layer edge bias in CSR order: ebias[i][h] (bf16) ----------------
__global__ void k_ebias(const int* __restrict__ eids, const float* __restrict__ efeat,
                        const float* __restrict__ Wcomb, const float* __restrict__ bcomb,
                        unsigned short* __restrict__ ebias) {
  int i = blockIdx.x * 256 + threadIdx.x;
  if (i >= EE) return;
  int e = eids[i];
  float4 ef = *(const float4*)(efeat + (size_t)e * EDI);
  ushort8 o;
#pragma unroll
  for (int hh = 0; hh < HH; hh++) {
    o[hh] = f2bf(bcomb[hh] + ef.x * Wcomb[hh] + ef.y * Wcomb[8 + hh] +
                 ef.z * Wcomb[16 + hh] + ef.w * Wcomb[24 + hh]);
  }
  *(ushort8*)(ebias + (size_t)i * 8) = o;
}

// ---------------- all-layers edge bias (prologue, when workspace allows) ----------------
__global__ void k_ebias_all(const int* __restrict__ eids, const float* __restrict__ efeat,
                            const float* __restrict__ WcombAll,
                            const float* __restrict__ bcombAll,
                            unsigned short* __restrict__ ebias6) {
  int i = blockIdx.x * 256 + threadIdx.x;
  if (i >= EE) return;
  int e = eids[i];
  float4 ef = *(const float4*)(efeat + (size_t)e * EDI);
#pragma unroll
  for (int l = 0; l < LL; l++) {
    const float* Wc = WcombAll + l * 32;
    const float* bc = bcombAll + l * 8;
    ushort8 o;
#pragma unroll
    for (int hh = 0; hh < HH; hh++) {
      o[hh] = f2bf(bc[hh] + ef.x * Wc[hh] + ef.y * Wc[8 + hh] +
                   ef.z * Wc[16 + hh] + ef.w * Wc[24 + hh]);
    }
    *(ushort8*)(ebias6 + ((size_t)l * EE + i) * 8) = o;
  }
}

// ---------------- LN1 + QKV projection via MFMA: 64 nodes/block, 4 waves ----------------
// outputs: q bf16 [node][128] (pre-scaled by 0.25 via packed Wq/bq), kf8, vf8 fp8
__global__ __launch_bounds__(256) void k_ln_qkv_mfma(
    const float* __restrict__ x,
    const unsigned short* __restrict__ Wqf, const float* __restrict__ bq,
    const unsigned short* __restrict__ Wkf, const float* __restrict__ bk,
    const unsigned short* __restrict__ Wvf, const float* __restrict__ bv,
    const float* __restrict__ g, const float* __restrict__ be,
    unsigned short* __restrict__ q, unsigned char* __restrict__ kf8,
    unsigned char* __restrict__ vf8) {
  __shared__ unsigned short xn[64][136];
  int t = threadIdx.x;
  int n0 = blockIdx.x * 64;
  {
    int row = t >> 2, quad = t & 3;   // 4 lanes/row, 32 elems each
    int node = n0 + row;
    float xv[32];
    float s = 0.f, sq = 0.f;
    if (node < NN) {
      const float* xr = x + (size_t)node * HDIM + quad * 32;
#pragma unroll
      for (int c = 0; c < 8; c++) {
        float4 f = *(const float4*)(xr + c * 4);
        xv[c*4+0]=f.x; xv[c*4+1]=f.y; xv[c*4+2]=f.z; xv[c*4+3]=f.w;
      }
#pragma unroll
      for (int j = 0; j < 32; j++) { s += xv[j]; sq += xv[j]*xv[j]; }
    } else {
#pragma unroll
      for (int j = 0; j < 32; j++) xv[j] = 0.f;
    }
    s += __shfl_xor(s, 1); s += __shfl_xor(s, 2);
    sq += __shfl_xor(sq, 1); sq += __shfl_xor(sq, 2);
    float m = s * (1.f / HDIM);
    float rv = rsqrtf(sq * (1.f / HDIM) - m * m + 1e-5f);
#pragma unroll
    for (int cb = 0; cb < 4; cb++) {
      ushort8 u;
#pragma unroll
      for (int j = 0; j < 8; j++) {
        int col = quad * 32 + cb * 8 + j;
        u[j] = f2bf((xv[cb*8+j] - m) * rv * g[col] + be[col]);
      }
      *(ushort8*)&xn[row][quad * 32 + cb * 8] = u;
    }
  }
  __syncthreads();
  int w = t >> 6, lane = t & 63;
  int r0 = w * 16;
  short8 a[4];
#pragma unroll
  for (int kc = 0; kc < 4; kc++)
    a[kc] = *(const short8*)&xn[r0 + (lane & 15)][kc * 32 + (lane >> 4) * 8];
  const unsigned short* Wf[3] = {Wqf, Wkf, Wvf};
  const float* bias[3] = {bq, bk, bv};
#pragma unroll
  for (int mm = 0; mm < 3; mm++) {
    const unsigned short* wf = Wf[mm];
    float bscale = (mm == 0) ? 0.25f : 1.0f;   // Wq pre-scaled by 0.25; scale bq to match
    for (int ct = 0; ct < 8; ct++) {
      floatx4 acc = {0.f, 0.f, 0.f, 0.f};
#pragma unroll
      for (int kc = 0; kc < 4; kc++) {
        short8 b = *(const short8*)(wf + ((size_t)(ct * 4 + kc) * 64 + lane) * 8);
        acc = __builtin_amdgcn_mfma_f32_16x16x32_bf16(a[kc], b, acc, 0, 0, 0);
      }
      int col = ct * 16 + (lane & 15);
      float bb = bias[mm][col] * bscale;
#pragma unroll
      for (int r = 0; r < 4; r++) {
        int rr = r0 + (lane >> 4) * 4 + r;
        int nd = n0 + rr;
        if (nd < NN) {
          float val = acc[r] + bb;
          if (mm == 0) q[(size_t)nd * HDIM + col] = f2bf(val);
          else if (mm == 1) kf8[(size_t)nd * HDIM + col] = f2fp8(val);
          else vf8[(size_t)nd * HDIM + col] = f2fp8(val);
        }
      }
    }
  }
}

// ---------------- attention: one 16-lane group per node, depth-4, fp8 K+V ----------------
__global__ __launch_bounds__(256) void k_attn(
    const unsigned short* __restrict__ q, const unsigned char* __restrict__ kf8,
    const unsigned char* __restrict__ vf8,
    const int* __restrict__ cols, const unsigned short* __restrict__ ebias,
    const int* __restrict__ starts,
    unsigned short* __restrict__ out) {
  int t = threadIdx.x;
  int wave = t >> 6, lane = t & 63;
  int g = lane >> 4, d = lane & 15;
  int node = blockIdx.x * 16 + wave * 4 + g;
  if (node >= NN) return;
  int hh = d >> 1;                      // head owned by this lane

  float qf[8];
  {
    ushort8 q8 = *(const ushort8*)(q + (size_t)node * HDIM + d * 8);
#pragma unroll
    for (int j = 0; j < 8; j++) qf[j] = bf2f(q8[j]);   // 0.25 scale pre-folded
  }

  int s0 = starts[node], s1 = starts[node + 1];
  float acc[8];
#pragma unroll
  for (int j = 0; j < 8; j++) acc[j] = 0.f;
  float lsum = 0.f;

  // depth-4 slots: data (k fp8, v fp8, bias) + pending (col, bias) for next edge
  uint2 sk[4], sv[4];
  float seb[4];
  int pc[4];
  float peb[4];

#pragma unroll
  for (int j = 0; j < 4; j++) {
    int i = s0 + j;
    bool ok = i < s1;
    int c = ok ? cols[i] : 0;
    sk[j] = *(const uint2*)(kf8 + (size_t)c * HDIM + d * 8);
    sv[j] = *(const uint2*)(vf8 + (size_t)c * HDIM + d * 8);
    seb[j] = ok ? bf2f(ebias[(size_t)i * 8 + hh]) : -1e30f;
  }
#pragma unroll
  for (int j = 0; j < 4; j++) {
    int i = s0 + 4 + j;
    bool ok = i < s1;
    pc[j] = ok ? cols[i] : 0;
    peb[j] = ok ? bf2f(ebias[(size_t)i * 8 + hh]) : -1e30f;
  }

  for (int base = s0; base < s1; base += 4) {
#pragma unroll
    for (int j = 0; j < 4; j++) {
      // stage data for edge (base+4+j)
      int c = pc[j];
      uint2 kn = *(const uint2*)(kf8 + (size_t)c * HDIM + d * 8);
      uint2 vn = *(const uint2*)(vf8 + (size_t)c * HDIM + d * 8);
      float ebn = peb[j];
      // stage ids/bias for edge (base+8+j)
      int i2 = base + 8 + j;
      bool ok2 = i2 < s1;
      int c2 = ok2 ? cols[i2] : 0;
      float eb2 = ok2 ? bf2f(ebias[(size_t)i2 * 8 + hh]) : -1e30f;
      // compute current slot j (edge base+j); invalid -> seb=-1e30 -> ex=0
      float kf[8], vf[8];
      fp8x8_dec(sk[j], kf);
      fp8x8_dec(sv[j], vf);
      float part = 0.f;
#pragma unroll
      for (int u = 0; u < 8; u++) part += qf[u] * kf[u];
      part += __shfl_xor(part, 1);
      float ex = __expf(part + seb[j]);
      lsum += ex;
#pragma unroll
      for (int u = 0; u < 8; u++) acc[u] += ex * vf[u];
      // rotate
      sk[j] = kn; sv[j] = vn; seb[j] = ebn;
      pc[j] = c2; peb[j] = eb2;
    }
  }

  float inv = 1.f / (lsum + 1e-10f);
  ushort8 o;
#pragma unroll
  for (int j = 0; j < 8; j++) o[j] = f2bf(acc[j] * inv);
  *(ushort8*)(out + (size_t)node * HDIM + d * 8) = o;
}

// ------- fused: oproj + residual + LN2 + FFN + residual (32 nodes/block, 4 waves) -------
// Proven round-10 version. Single 34.3 KB LDS pool with phased aliasing:
//   phase 1: aos bf16 [32][136] at off 0 shorts; xr fp32 [32][132] at off 8704 shorts
//   phase 2 (post-oproj): residual lives in racc[4][4] regs; xn bf16 [32][136] at off 0
//   phase 3: hidden hs bf16 [32] rows x 512 cols, row stride 536 shorts (full pool)
__global__ __launch_bounds__(256) void k_oproj_ffn(
    const unsigned short* __restrict__ ao, const unsigned short* __restrict__ Wof,
    const float* __restrict__ bo,
    const unsigned short* __restrict__ W1f, const float* __restrict__ b1,
    const unsigned short* __restrict__ W2f, const float* __restrict__ b2,
    const float* __restrict__ g, const float* __restrict__ be,
    float* __restrict__ x) {
  __shared__ unsigned short pool[32 * 536];        // 34304 B
  unsigned short* aosp = pool;                     // [row*136+col]
  float* xrp = (float*)(pool + 8704);              // [row*132+col], 16896 B
  unsigned short* xnp = pool;                      // reuses aos region
  int t = threadIdx.x;
  int n0 = blockIdx.x * 32;

  // Stage A: load ao tile (bf16, coalesced) and x tile (fp32, coalesced)
#pragma unroll
  for (int c = 0; c < 2; c++) {
    int elem = c * 2048 + t * 8;
    int row = elem >> 7, col = elem & 127;
    int nd = n0 + row;
    ushort8 u = {0, 0, 0, 0, 0, 0, 0, 0};
    if (nd < NN) u = *(const ushort8*)(ao + (size_t)nd * HDIM + col);
    *(ushort8*)&aosp[row * 136 + col] = u;
  }
#pragma unroll
  for (int c = 0; c < 4; c++) {
    int elem = c * 1024 + t * 4;
    int row = elem >> 7, col = elem & 127;
    int nd = n0 + row;
    float4 f = {0.f, 0.f, 0.f, 0.f};
    if (nd < NN) f = *(const float4*)(x + (size_t)nd * HDIM + col);
    *(float4*)&xrp[row * 132 + col] = f;
  }
  __syncthreads();

  int w = t >> 6, lane = t & 63;
  int rt = w & 1, r0 = rt * 16;
  int cthalf = w >> 1;
  int lcol = lane & 15, lrow8 = (lane >> 4) * 8, lrow4 = (lane >> 4) * 4;

  // oproj: racc = x + ao @ Wo + bo  (kept in regs, C layout) ; also written to xr for LN
  float racc[4][4];
  {
    short8 a[4];
#pragma unroll
    for (int kc = 0; kc < 4; kc++)
      a[kc] = *(const short8*)&aosp[(r0 + lcol) * 136 + kc * 32 + lrow8];
#pragma unroll
    for (int ci = 0; ci < 4; ci++) {
      int ct = cthalf * 4 + ci;
      floatx4 acc = {0.f, 0.f, 0.f, 0.f};
#pragma unroll
      for (int kc = 0; kc < 4; kc++) {
        short8 b = *(const short8*)(Wof + ((size_t)(ct * 4 + kc) * 64 + lane) * 8);
        acc = __builtin_amdgcn_mfma_f32_16x16x32_bf16(a[kc], b, acc, 0, 0, 0);
      }
      int col = ct * 16 + lcol;
      float bb = bo[col];
#pragma unroll
      for (int r = 0; r < 4; r++) {
        int rr = r0 + lrow4 + r;
        float v = xrp[rr * 132 + col] + acc[r] + bb;
        racc[ci][r] = v;
        xrp[rr * 132 + col] = v;
      }
    }
  }
  __syncthreads();

  // LN2 from xr -> xn at pool offset 0 (aos dead); 8 lanes/row
  {
    int row = t >> 3, oct = t & 7;
    float xv[16];
    float s = 0.f, sq = 0.f;
#pragma unroll
    for (int jj = 0; jj < 16; jj++) {
      float f = xrp[row * 132 + oct * 16 + jj];
      xv[jj] = f; s += f; sq += f * f;
    }
    s += __shfl_xor(s, 1); s += __shfl_xor(s, 2); s += __shfl_xor(s, 4);
    sq += __shfl_xor(sq, 1); sq += __shfl_xor(sq, 2); sq += __shfl_xor(sq, 4);
    float m = s * (1.f / HDIM);
    float rv = rsqrtf(sq * (1.f / HDIM) - m * m + 1e-5f);
#pragma unroll
    for (int cb = 0; cb < 2; cb++) {
      ushort8 u;
#pragma unroll
      for (int jj = 0; jj < 8; jj++) {
        int col = oct * 16 + cb * 8 + jj;
        u[jj] = f2bf((xv[cb*8+jj] - m) * rv * g[col] + be[col]);
      }
      *(ushort8*)&xnp[row * 136 + oct * 16 + cb * 8] = u;
    }
  }
  __syncthreads();

  // load GEMM1 A-fragments from xn BEFORE the pool is overwritten by hs
  short8 axn[4];
#pragma unroll
  for (int kc = 0; kc < 4; kc++)
    axn[kc] = *(const short8*)&xnp[(r0 + lcol) * 136 + kc * 32 + lrow8];
  __syncthreads();   // all xn reads done; pool free for hidden

  // GEMM1: hidden = relu(xn @ W1 + b1) -> pool rows stride 536
  for (int ci = 0; ci < 16; ci++) {
    int ct = cthalf * 16 + ci;
    floatx4 acc = {0.f, 0.f, 0.f, 0.f};
#pragma unroll
    for (int kc = 0; kc < 4; kc++) {
      short8 b = *(const short8*)(W1f + ((size_t)(ct * 4 + kc) * 64 + lane) * 8);
      acc = __builtin_amdgcn_mfma_f32_16x16x32_bf16(axn[kc], b, acc, 0, 0, 0);
    }
    int col = ct * 16 + lcol;
    float bb = b1[col];
#pragma unroll
    for (int r = 0; r < 4; r++) {
      pool[(r0 + lrow4 + r) * 536 + col] = f2bf(fmaxf(acc[r] + bb, 0.f));
    }
  }
  __syncthreads();

  // GEMM2: x = hidden @ W2 + b2 + racc
  {
    short8 ah[16];
#pragma unroll
    for (int kc = 0; kc < 16; kc++)
      ah[kc] = *(const short8*)&pool[(r0 + lcol) * 536 + kc * 32 + lrow8];
#pragma unroll
    for (int ci = 0; ci < 4; ci++) {
      int ct2 = cthalf * 4 + ci;
      floatx4 acc = {0.f, 0.f, 0.f, 0.f};
#pragma unroll
      for (int kc = 0; kc < 16; kc++) {
        short8 b = *(const short8*)(W2f + ((size_t)(ct2 * 16 + kc) * 64 + lane) * 8);
        acc = __builtin_amdgcn_mfma_f32_16x16x32_bf16(ah[kc], b, acc, 0, 0, 0);
      }
      int col = ct2 * 16 + lcol;
      float bb = b2[col];
#pragma unroll
      for (int r = 0; r < 4; r++) {
        int nd = n0 + r0 + lrow4 + r;
        if (nd < NN) x[(size_t)nd * HDIM + col] = racc[ci][r] + acc[r] + bb;
      }
    }
  }
}

// ---------------- final LN -> d_out (vectorized, 64 nodes/block) ----------------
__global__ __launch_bounds__(256) void k_final(
    const float* __restrict__ x, const float* __restrict__ g,
    const float* __restrict__ be, float* __restrict__ outx) {
  int t = threadIdx.x;
  int row = t >> 2, quad = t & 3;      // 4 lanes/row, 32 elems each
  int node = blockIdx.x * 64 + row;
  if (node >= NN) return;
  const float* xr = x + (size_t)node * HDIM + quad * 32;
  float xv[32];
  float s = 0.f, sq = 0.f;
#pragma unroll
  for (int c = 0; c < 8; c++) {
    float4 f = *(const float4*)(xr + c * 4);
    xv[c*4+0]=f.x; xv[c*4+1]=f.y; xv[c*4+2]=f.z; xv[c*4+3]=f.w;
  }
#pragma unroll
  for (int j = 0; j < 32; j++) { s += xv[j]; sq += xv[j]*xv[j]; }
  s += __shfl_xor(s, 1); s += __shfl_xor(s, 2);
  sq += __shfl_xor(sq, 1); sq += __shfl_xor(sq, 2);
  float m = s * (1.f / HDIM);
  float rv = rsqrtf(sq * (1.f / HDIM) - m * m + 1e-5f);
  float* orow = outx + (size_t)node * HDIM + quad * 32;
#pragma unroll
  for (int c = 0; c < 8; c++) {
    float4 o;
    int col = quad * 32 + c * 4;
    o.x = (xv[c*4+0] - m) * rv * g[col+0] + be[col+0];
    o.y = (xv[c*4+1] - m) * rv * g[col+1] + be[col+1];
    o.z = (xv[c*4+2] - m) * rv * g[col+2] + be[col+2];
    o.w = (xv[c*4+3] - m) * rv * g[col+3] + be[col+3];
    *(float4*)(orow + c * 4) = o;
  }
}

// ---------------- graph mean pooling (batch is sorted; counts from gstart) ----------------
__global__ void k_pool(const float* __restrict__ outx, const int* __restrict__ gstart,
                       float* __restrict__ outg) {
  __shared__ float part[4][HDIM];
  int g = blockIdx.x;
  int t = threadIdx.x;  // 512
  int hd = t & 127, p = t >> 7;
  int s0 = gstart[g];
  int c = gstart[g + 1] - s0;
  float s = 0.f;
  for (int i = p; i < c; i += 4) s += outx[(size_t)(s0 + i) * HDIM + hd];
  part[p][hd] = s;
  __syncthreads();
  if (p == 0) {
    float tot = part[0][hd] + part[1][hd] + part[2][hd] + part[3][hd];
    outg[g * HDIM + hd] = tot / fmaxf((float)c, 1.f);
  }
}

extern "C" void kernel_launch(void* const* d_in, const int* in_sizes, int n_in,
                              void* d_out, int out_size, void* d_ws, size_t ws_size,
                              hipStream_t stream) {
  const float* h      = (const float*)d_in[0];
  const float* e      = (const float*)d_in[1];
  const int*   eidx   = (const int*)d_in[2];
  const int*   batch  = (const int*)d_in[3];
  const float* node_W = (const float*)d_in[4];
  const float* node_b = (const float*)d_in[5];
  const float* edge_W = (const float*)d_in[6];
  const float* edge_b = (const float*)d_in[7];
  const float* Wq  = (const float*)d_in[8];
  const float* bq  = (const float*)d_in[9];
  const float* Wk  = (const float*)d_in[10];
  const float* bk  = (const float*)d_in[11];
  const float* Wv  = (const float*)d_in[12];
  const float* bv  = (const float*)d_in[13];
  const float* Wo  = (const float*)d_in[14];
  const float* bo  = (const float*)d_in[15];
  const float* Web = (const float*)d_in[16];
  const float* beb = (const float*)d_in[17];
  const float* W1  = (const float*)d_in[18];
  const float* b1  = (const float*)d_in[19];
  const float* W2  = (const float*)d_in[20];
  const float* b2  = (const float*)d_in[21];
  const float* g1  = (const float*)d_in[22];
  const float* be1 = (const float*)d_in[23];
  const float* g2  = (const float*)d_in[24];
  const float* be2 = (const float*)d_in[25];
  const float* gF  = (const float*)d_in[26];
  const float* bF  = (const float*)d_in[27];

  const int* rowArr = eidx;
  const int* colArr = eidx + EE;

  char* ws = (char*)d_ws;
  size_t off = 0;
  auto alloc = [&](size_t bytes) -> void* {
    void* p = ws + off;
    off = (off + bytes + 255) & ~(size_t)255;
    return p;
  };
  float* x    = (float*)alloc((size_t)NN * HDIM * 4);
  unsigned short* qb  = (unsigned short*)alloc((size_t)NN * HDIM * 2);
  unsigned char*  kf8 = (unsigned char*)alloc((size_t)NN * HDIM);
  unsigned char*  vf8 = (unsigned char*)alloc((size_t)NN * HDIM);
  unsigned short* ao  = (unsigned short*)alloc((size_t)NN * HDIM * 2);
  int* deg    = (int*)alloc((size_t)NN * 4);
  int* starts = (int*)alloc((size_t)(NN + 1) * 4);
  int* cursor = (int*)alloc((size_t)NN * 4);
  int* eids   = (int*)alloc((size_t)EE * 4);
  int* cols   = (int*)alloc((size_t)EE * 4);
  unsigned short* ebias = (unsigned short*)alloc((size_t)EE * HH * 2);
  int* bsum   = (int*)alloc((size_t)SCB * 4);
  float* Wcomb = (float*)alloc((size_t)LL * EDI * HH * 4);
  float* bcomb = (float*)alloc((size_t)LL * HH * 4);
  int* gstart = (int*)alloc((size_t)(GG + 1) * 4);
  // fragment-packed bf16 weights
  const int QKV_FRAG = 8 * 4 * 512;    // 16384 elems per matrix per layer
  const int FFN_FRAG1 = 32 * 4 * 512;  // 65536
  const int FFN_FRAG2 = 8 * 16 * 512;  // 65536
  unsigned short* Wqf = (unsigned short*)alloc((size_t)LL * QKV_FRAG * 2);
  unsigned short* Wkf = (unsigned short*)alloc((size_t)LL * QKV_FRAG * 2);
  unsigned short* Wvf = (unsigned short*)alloc((size_t)LL * QKV_FRAG * 2);
  unsigned short* Wof = (unsigned short*)alloc((size_t)LL * QKV_FRAG * 2);
  unsigned short* W1f = (unsigned short*)alloc((size_t)LL * FFN_FRAG1 * 2);
  unsigned short* W2f = (unsigned short*)alloc((size_t)LL * FFN_FRAG2 * 2);

  // all-layers ebias if workspace permits (deterministic: depends only on ws_size)
  size_t need6 = (size_t)LL * EE * HH * 2;
  unsigned short* ebias6 = nullptr;
  if (off + need6 + 256 <= ws_size) ebias6 = (unsigned short*)alloc(need6);

  hipMemsetAsync(deg, 0, (size_t)NN * 4, stream);

  k_node_proj<<<(NN + 31) / 32, 128, 0, stream>>>(h, node_W, node_b, x);
  k_wcomb<<<1, 256, 0, stream>>>(edge_W, edge_b, Web, beb, Wcomb, bcomb);
  k_pack_all<<<(PACK_TOT + 255) / 256, 256, 0, stream>>>(Wq, Wk, Wv, Wo, W1, W2,
                                                         Wqf, Wkf, Wvf, Wof, W1f, W2f);
  k_deg<<<(EE + 255) / 256, 256, 0, stream>>>(rowArr, deg);
  k_scan1<<<SCB, 256, 0, stream>>>(deg, bsum);
  k_scan2<<<1, 64, 0, stream>>>(bsum, starts);
  k_scan3<<<SCB, 256, 0, stream>>>(deg, bsum, starts, cursor);
  k_scatter<<<(EE + 255) / 256, 256, 0, stream>>>(rowArr, colArr, cursor, eids, cols);
  k_gbounds<<<(NN + 255) / 256, 256, 0, stream>>>(batch, gstart);

  int nb64 = (NN + 63) / 64;
  int nb32 = (NN + 31) / 32;
  int nb16 = (NN + 15) / 16;
  int nbE  = (EE + 255) / 256;

  if (ebias6) {
    k_ebias_all<<<nbE, 256, 0, stream>>>(eids, e, Wcomb, bcomb, ebias6);
  }

  for (int l = 0; l < LL; l++) {
    k_ln_qkv_mfma<<<nb64, 256, 0, stream>>>(x,
        Wqf + (size_t)l * QKV_FRAG, bq + (size_t)l * HDIM,
        Wkf + (size_t)l * QKV_FRAG, bk + (size_t)l * HDIM,
        Wvf + (size_t)l * QKV_FRAG, bv + (size_t)l * HDIM,
        g1 + (size_t)l * HDIM, be1 + (size_t)l * HDIM, qb, kf8, vf8);
    const unsigned short* eb_l;
    if (ebias6) {
      eb_l = ebias6 + (size_t)l * EE * HH;
    } else {
      k_ebias<<<nbE, 256, 0, stream>>>(eids, e,
          Wcomb + (size_t)l * EDI * HH, bcomb + (size_t)l * HH, ebias);
      eb_l = ebias;
    }
    k_attn<<<nb16, 256, 0, stream>>>(qb, kf8, vf8, cols, eb_l, starts, ao);
    k_oproj_ffn<<<nb32, 256, 0, stream>>>(ao, Wof + (size_t)l * QKV_FRAG,
        bo + (size_t)l * HDIM,
        W1f + (size_t)l * FFN_FRAG1, b1 + (size_t)l * FFD,
        W2f + (size_t)l * FFN_FRAG2, b2 + (size_t)l * HDIM,
        g2 + (size_t)l * HDIM, be2 + (size_t)l * HDIM, x);
  }

  float* outx = (float*)d_out;
  float* outg = outx + (size_t)NN * HDIM;
  k_final<<<(NN + 63) / 64, 256, 0, stream>>>(x, gF, bF, outx);
  k_pool<<<GG, 512, 0, stream>>>(outx, gstart, outg);
}